// Round 1
// baseline (2296.895 us; speedup 1.0000x reference)
//
#include <hip/hip_runtime.h>
#include <math.h>

// Problem constants (fixed by setup_inputs)
#define BQ    1024      // queries
#define NB    131072    // blobs
#define DS    64        // spatial dim
#define DF    256       // feature dim
#define KSEL  16        // top-k

// Score kernel tiling
#define QT    64        // queries per tile (grid.y = BQ/QT = 16)
#define BC    64        // blobs per chunk
#define KDIM  128       // 2*DS (concat [q^2 ; -2q] x [iv ; mu*iv])
#define LDT   68        // padded LDS leading dim (68*4 B = 272 = 16*17, 16B-aligned rows)
#define SLD   65        // score-tile leading dim (bank-spread for the scan)
#define PCH   32        // chunk-blocks per query tile (grid.x)
#define NCHUNK (NB / BC)        // 2048
#define CPQ   (PCH * KSEL)      // 512 candidates per query

__global__ __launch_bounds__(256, 2)
void score_topk_kernel(const float* __restrict__ query,
                       const float* __restrict__ mu,
                       const float* __restrict__ log_var,
                       const float* __restrict__ raw_alpha,
                       const float* __restrict__ log_tau_p,
                       float* __restrict__ cand_s,
                       int* __restrict__ cand_i)
{
    __shared__ float At[KDIM][LDT];   // queries:  [0:64)=q^2, [64:128)=-2q  (k-major)
    __shared__ float Bt[KDIM][LDT];   // blobs:    [0:64)=iv,  [64:128)=mu*iv (k-major); reused as S-tile
    __shared__ float Sm2[BC];
    __shared__ float Sal[BC];
    __shared__ float top_s[QT][17];   // padded: (17q+s)%32 spreads banks
    __shared__ int   top_i[QT][17];

    const int tid   = threadIdx.x;
    const int qtile = blockIdx.y;
    const int qbase = qtile * QT;

    const float nhit = -0.5f * expf(-log_tau_p[0]);   // -0.5 / tau

    // ---- stage queries -> At (once per block), coalesced global reads ----
    for (int it = 0; it < (QT * DS) / 256; ++it) {
        int idx = tid + it * 256;
        int ql = idx >> 6;         // query within tile
        int d  = idx & 63;
        float v = query[(size_t)(qbase + ql) * DS + d];
        At[d][ql]      = v * v;
        At[d + DS][ql] = -2.0f * v;
    }
    {
        float* ts = &top_s[0][0];
        int*   ti = &top_i[0][0];
        for (int idx = tid; idx < QT * 17; idx += 256) {
            ts[idx] = -INFINITY;
            ti[idx] = 0x7FFFFFFF;
        }
    }

    const int tx = tid & 15;    // blob group  (4 blobs)
    const int ty = tid >> 4;    // query group (4 queries)

    for (int c = blockIdx.x; c < NCHUNK; c += PCH) {
        const int nbase = c * BC;
        __syncthreads();   // previous scan done; Bt/Sm2 safe to overwrite

        // ---- stage blob chunk: iv, mu*iv, m2, alpha ----
        for (int it = 0; it < (BC * DS) / 256; ++it) {
            int idx = tid + it * 256;
            int nl = idx >> 6;          // whole wave shares nl
            int d  = idx & 63;
            size_t g = (size_t)(nbase + nl) * DS + d;
            float m  = mu[g];
            float iv = expf(-log_var[g]);
            float mv = m * iv;
            Bt[d][nl]      = iv;
            Bt[d + DS][nl] = mv;
            float p = m * mv;           // mu^2 * iv
            #pragma unroll
            for (int off = 32; off > 0; off >>= 1) p += __shfl_down(p, off);
            if (d == 0) Sm2[nl] = p;
        }
        if (tid < BC)
            Sal[tid] = 1.0f / (1.0f + expf(-raw_alpha[nbase + tid]));
        __syncthreads();

        // ---- 64x64 score tile, 4x4 per-thread register tile, K=128 ----
        float acc[4][4];
        #pragma unroll
        for (int i = 0; i < 4; ++i)
            #pragma unroll
            for (int j = 0; j < 4; ++j) acc[i][j] = 0.0f;

        #pragma unroll 4
        for (int kk = 0; kk < KDIM; ++kk) {
            float4 av = *reinterpret_cast<const float4*>(&At[kk][ty << 2]);
            float4 bv = *reinterpret_cast<const float4*>(&Bt[kk][tx << 2]);
            float a4[4] = {av.x, av.y, av.z, av.w};
            float b4[4] = {bv.x, bv.y, bv.z, bv.w};
            #pragma unroll
            for (int i = 0; i < 4; ++i)
                #pragma unroll
                for (int j = 0; j < 4; ++j)
                    acc[i][j] += a4[i] * b4[j];
        }

        // ---- epilogue: score = alpha * exp(-0.5*mahal/tau) ----
        float m2v[4], alv[4];
        #pragma unroll
        for (int j = 0; j < 4; ++j) {
            m2v[j] = Sm2[(tx << 2) + j];
            alv[j] = Sal[(tx << 2) + j];
        }
        #pragma unroll
        for (int i = 0; i < 4; ++i)
            #pragma unroll
            for (int j = 0; j < 4; ++j)
                acc[i][j] = alv[j] * expf(nhit * (acc[i][j] + m2v[j]));

        __syncthreads();   // all Bt reads done -> reuse as S-tile
        float* Stile = &Bt[0][0];
        #pragma unroll
        for (int i = 0; i < 4; ++i)
            #pragma unroll
            for (int j = 0; j < 4; ++j)
                Stile[((ty << 2) + i) * SLD + (tx << 2) + j] = acc[i][j];
        __syncthreads();

        // ---- per-query insertion into sorted top-16 (jax tie semantics) ----
        if (tid < QT) {
            const int q = tid;
            for (int nl = 0; nl < BC; ++nl) {
                float s = Stile[q * SLD + nl];
                if (s > top_s[q][KSEL - 1]) {      // strict: equal loses to earlier idx
                    int p = KSEL - 1;
                    while (p > 0 && top_s[q][p - 1] < s) {   // stable among equals
                        top_s[q][p] = top_s[q][p - 1];
                        top_i[q][p] = top_i[q][p - 1];
                        --p;
                    }
                    top_s[q][p] = s;
                    top_i[q][p] = nbase + nl;
                }
            }
        }
    }
    __syncthreads();

    // ---- write candidates ----
    for (int idx = tid; idx < QT * KSEL; idx += 256) {
        int ql = idx >> 4, sl = idx & 15;
        size_t o = (size_t)(qbase + ql) * CPQ + blockIdx.x * KSEL + sl;
        cand_s[o] = top_s[ql][sl];
        cand_i[o] = top_i[ql][sl];
    }
}

__global__ __launch_bounds__(256)
void merge_composite_kernel(const float* __restrict__ query,
                            const float* __restrict__ mu,
                            const float* __restrict__ log_var,
                            const float* __restrict__ raw_alpha,
                            const float* __restrict__ features,
                            const float* __restrict__ log_tau_p,
                            const float* __restrict__ cand_s,
                            const int* __restrict__ cand_i,
                            float* __restrict__ out)
{
    const int q   = blockIdx.x;
    const int tid = threadIdx.x;

    __shared__ unsigned long long keys[CPQ];
    __shared__ unsigned long long rkey[256];
    __shared__ int   rpos[256];
    __shared__ int   sel[KSEL];
    __shared__ float w_sh[KSEL];
    __shared__ float mah[KSEL];
    __shared__ float alp[KSEL];

    // pack (score, idx) -> monotone u64 key; scores are strictly > 0
    for (int i = tid; i < CPQ; i += 256) {
        float s = cand_s[(size_t)q * CPQ + i];
        int  gi = cand_i[(size_t)q * CPQ + i];
        unsigned long long key = 0ull;
        if (s > 0.0f)
            key = ((unsigned long long)__float_as_uint(s) << 32) |
                  (unsigned long long)(0xFFFFFFFFu - (unsigned)gi);
        keys[i] = key;
    }
    __syncthreads();

    // 16 rounds of block-wide argmax (descending score, ascending idx on tie)
    for (int r = 0; r < KSEL; ++r) {
        unsigned long long k1 = keys[tid], k2 = keys[tid + 256];
        if (k2 > k1) { rkey[tid] = k2; rpos[tid] = tid + 256; }
        else         { rkey[tid] = k1; rpos[tid] = tid; }
        __syncthreads();
        for (int off = 128; off > 0; off >>= 1) {
            if (tid < off && rkey[tid + off] > rkey[tid]) {
                rkey[tid] = rkey[tid + off];
                rpos[tid] = rpos[tid + off];
            }
            __syncthreads();
        }
        if (tid == 0) {
            unsigned long long kw = rkey[0];
            sel[r] = (int)(0xFFFFFFFFu - (unsigned)(kw & 0xFFFFFFFFull));
            keys[rpos[0]] = 0ull;
        }
        __syncthreads();
    }

    // exact mahal per selected blob (direct gathered form, like reference)
    const int wv = tid >> 6, lane = tid & 63;
    for (int r = wv; r < KSEL; r += 4) {
        int bi = sel[r];
        float qd = query[(size_t)q * DS + lane];
        float m  = mu[(size_t)bi * DS + lane];
        float d  = qd - m;
        float t  = d * d * expf(-log_var[(size_t)bi * DS + lane]);
        #pragma unroll
        for (int off = 32; off > 0; off >>= 1) t += __shfl_down(t, off);
        if (lane == 0) {
            mah[r] = t;
            alp[r] = 1.0f / (1.0f + expf(-raw_alpha[bi]));
        }
    }
    __syncthreads();

    // serial log-space compositing (16 steps)
    if (tid == 0) {
        float tau = expf(log_tau_p[0]);
        float cap = 0.3f / 16.0f;          // T_MAX / k
        float logT = 0.0f;
        for (int r = 0; r < KSEL; ++r) {
            float K   = expf(-0.5f * mah[r] / tau);
            float eff = fminf(alp[r] * K, cap);
            w_sh[r]   = eff * expf(logT);
            logT     += log1pf(-fminf(eff, 1.0f - 1e-6f));
        }
        out[(size_t)BQ * DF + q] = expf(logT);   // t_residual
    }
    __syncthreads();

    // weighted feature sum (coalesced)
    {
        float a = 0.0f;
        #pragma unroll
        for (int r = 0; r < KSEL; ++r)
            a += w_sh[r] * features[(size_t)sel[r] * DF + tid];
        out[(size_t)q * DF + tid] = a;
    }
}

extern "C" void kernel_launch(void* const* d_in, const int* in_sizes, int n_in,
                              void* d_out, int out_size, void* d_ws, size_t ws_size,
                              hipStream_t stream)
{
    (void)in_sizes; (void)n_in; (void)out_size; (void)ws_size;
    const float* query     = (const float*)d_in[0];
    const float* mu        = (const float*)d_in[1];
    const float* log_var   = (const float*)d_in[2];
    const float* raw_alpha = (const float*)d_in[3];
    const float* features  = (const float*)d_in[4];
    const float* log_tau   = (const float*)d_in[5];
    float* out = (float*)d_out;

    float* cand_s = (float*)d_ws;
    int*   cand_i = (int*)((char*)d_ws + (size_t)BQ * CPQ * sizeof(float));

    dim3 g2(PCH, BQ / QT);
    score_topk_kernel<<<g2, 256, 0, stream>>>(query, mu, log_var, raw_alpha,
                                              log_tau, cand_s, cand_i);
    merge_composite_kernel<<<BQ, 256, 0, stream>>>(query, mu, log_var, raw_alpha,
                                                   features, log_tau,
                                                   cand_s, cand_i, out);
}